// Round 22
// baseline (42.536 us; speedup 1.0000x reference)
//
#include <hip/hip_runtime.h>

#define DIM     400
#define NENT    14541
#define B       32
#define NCAND   14505
#define NBLK    455       // each block: 16 pairs = 32 candidates -> 14560 >= NCAND
#define THREADS 512

typedef __attribute__((ext_vector_type(2))) _Float16 half2_t;

static __device__ __forceinline__ half2_t bch(unsigned u) {
    return __builtin_bit_cast(half2_t, u);
}
static __device__ __forceinline__ half2_t habs2(half2_t x) {
    unsigned u = __builtin_bit_cast(unsigned, x) & 0x7fff7fffu;
    return __builtin_bit_cast(half2_t, u);
}
static __device__ __forceinline__ unsigned pkh(float x, float y) {
    half2_t h;
    h.x = (_Float16)x;
    h.y = (_Float16)y;
    return __builtin_bit_cast(unsigned, h);
}
static __device__ __forceinline__ float dot2acc(half2_t m, float s) {
#if __has_builtin(__builtin_amdgcn_fdot2)
    const half2_t ones = {(_Float16)1.f, (_Float16)1.f};
    return __builtin_amdgcn_fdot2(m, ones, s, false);
#else
    return s + (float)m.x + (float)m.y;
#endif
}

// ---- single fused kernel: no workspace, no setup launch ----
// Prologue: block builds transposed q/o f16 tables in LDS ([j][b], 51.2 KB) from
// ent/relc/relo (L2-hot: same 64 rows for every block) + deterministic base[b].
// Main: wave = 2 cand-slots x 32 batches, TWO pairs per j-pass: qj/oj ds_read ONCE
// per wave per j, applied to 4 candidates (LDS instrs halved vs R21); candidate rows
// read straight from ent via cidx (broadcast across 32 b-lanes) with on-the-fly
// f32->f16 pack — dense16 table, its 35 MB setup traffic, and the launch dependency
// are deleted. 512-thr blocks -> 2 waves/SIMD at 53 KB LDS (R21 had 1).
__global__ __launch_bounds__(THREADS, 2)
void score_fused(const float* __restrict__ ent,
                 const float* __restrict__ relc,
                 const float* __restrict__ relo,
                 const float* __restrict__ onev,
                 const int*   __restrict__ pairs,
                 const int*   __restrict__ cidx,
                 float* __restrict__ out) {
    __shared__ uint4 qs[1600];           // [j][b], j=0..49, b=0..31
    __shared__ uint4 os[1600];           // pre-scaled 0.98*o
    __shared__ float bpart[THREADS];
    __shared__ float base_s[B];

    const int tid = threadIdx.x;

    // ---- prologue: q/o tables + base ----
    float part = 0.f;
    for (int i = tid; i < 1600; i += THREADS) {   // i = j*32+b; b == tid&31 (512%32==0)
        const int j = i >> 5;
        const int b = i & 31;
        const int h = pairs[2 * b + 0];
        const int r = pairs[2 * b + 1];
        const float4* hp = (const float4*)(ent  + (size_t)h * DIM) + 2 * j;
        const float4* cp = (const float4*)(relc + (size_t)r * DIM) + 2 * j;
        const float4* op = (const float4*)(relo + (size_t)r * DIM) + 2 * j;
        float4 h0 = hp[0], h1 = hp[1];
        float4 c0 = cp[0], c1 = cp[1];
        float4 v0 = op[0], v1 = op[1];
        uint4 qv, ov;
        qv.x = pkh(h0.x + c0.x, h0.y + c0.y);
        qv.y = pkh(h0.z + c0.z, h0.w + c0.w);
        qv.z = pkh(h1.x + c1.x, h1.y + c1.y);
        qv.w = pkh(h1.z + c1.z, h1.w + c1.w);
        ov.x = pkh(0.98f * v0.x, 0.98f * v0.y);
        ov.y = pkh(0.98f * v0.z, 0.98f * v0.w);
        ov.z = pkh(0.98f * v1.x, 0.98f * v1.y);
        ov.w = pkh(0.98f * v1.z, 0.98f * v1.w);
        qs[i] = qv;
        os[i] = ov;
        part += v0.x + v0.y + v0.z + v0.w + v1.x + v1.y + v1.z + v1.w;
    }
    bpart[tid] = part;
    __syncthreads();
    if (tid < B) {                        // deterministic: threads tid+32k share batch tid
        float s = 0.f;
#pragma unroll
        for (int k = 0; k < THREADS / 32; ++k) s += bpart[tid + 32 * k];
        base_s[tid] = onev[0] + 0.98f * s;
    }
    __syncthreads();

    // ---- main ----
    const int wid  = tid >> 6;            // 0..7
    const int lane = tid & 63;
    const int b    = lane & 31;           // batch
    const int c2   = lane >> 5;           // candidate within pair
    const float base = base_s[b];

    const int p0    = blockIdx.x * 16 + wid * 2;
    const int candA = 2 * p0 + c2;
    const int candB = 2 * (p0 + 1) + c2;
    const int ciA = cidx[candA < NCAND ? candA : NCAND - 1];
    const int ciB = cidx[candB < NCAND ? candB : NCAND - 1];
    const float4* rA = (const float4*)(ent + (size_t)ciA * DIM);
    const float4* rB = (const float4*)(ent + (size_t)ciB * DIM);

    const half2_t K002 = {(_Float16)0.02f, (_Float16)0.02f};

#define PAIRE(cu, qu, ou, SS)                                   \
    {                                                           \
        half2_t cc_ = bch(cu), qq_ = bch(qu), oo_ = bch(ou);    \
        half2_t dd_ = cc_ - qq_;                                \
        half2_t aa_ = habs2(dd_);                               \
        half2_t ee_ = aa_ * K002 + oo_;                         \
        half2_t mm_ = __builtin_elementwise_max(aa_, ee_);      \
        SS = dot2acc(mm_, SS);                                  \
    }
#define PROC(C, Q, O, SA, SB)                                   \
    PAIRE(C.x, Q.x, O.x, SA) PAIRE(C.y, Q.y, O.y, SB)           \
    PAIRE(C.z, Q.z, O.z, SA) PAIRE(C.w, Q.w, O.w, SB)

    float sA0 = 0.f, sA1 = 0.f, sB0 = 0.f, sB1 = 0.f;
#pragma unroll 5
    for (int j = 0; j < 50; ++j) {
        float4 a0 = rA[2 * j], a1 = rA[2 * j + 1];
        float4 e0 = rB[2 * j], e1 = rB[2 * j + 1];
        uint4 ca, ce;
        ca.x = pkh(a0.x, a0.y); ca.y = pkh(a0.z, a0.w);
        ca.z = pkh(a1.x, a1.y); ca.w = pkh(a1.z, a1.w);
        ce.x = pkh(e0.x, e0.y); ce.y = pkh(e0.z, e0.w);
        ce.z = pkh(e1.x, e1.y); ce.w = pkh(e1.z, e1.w);
        const uint4 qj = qs[(j << 5) | b];
        const uint4 oj = os[(j << 5) | b];
        PROC(ca, qj, oj, sA0, sA1)
        PROC(ce, qj, oj, sB0, sB1)
    }
#undef PROC
#undef PAIRE

    if (candA < NCAND)
        out[(size_t)b * NCAND + candA] = base - (sA0 + sA1);
    if (candB < NCAND)
        out[(size_t)b * NCAND + candB] = base - (sB0 + sB1);
}

extern "C" void kernel_launch(void* const* d_in, const int* in_sizes, int n_in,
                              void* d_out, int out_size, void* d_ws, size_t ws_size,
                              hipStream_t stream) {
    const float* ent   = (const float*)d_in[0];
    const float* relc  = (const float*)d_in[1];
    const float* relo  = (const float*)d_in[2];
    const float* onev  = (const float*)d_in[3];
    const int*   pairs = (const int*)d_in[4];
    const int*   cidx  = (const int*)d_in[5];
    float*       out   = (float*)d_out;

    score_fused<<<NBLK, THREADS, 0, stream>>>(ent, relc, relo, onev, pairs, cidx, out);
}

// Round 23
// 40.239 us; speedup vs baseline: 1.0571x; 1.0571x over previous
//
#include <hip/hip_runtime.h>

#define DIM     400
#define NENT    14541
#define B       32
#define NCAND   14505
#define DROWS   14560     // padded dense rows (455 blocks x 32 cands)
#define CVTN    (DROWS * 50)                 // 728000 uint4
#define CVTBLK  ((CVTN + 255) / 256)         // 2844
#define NBLK    455       // score blocks: 16 pairs = 32 cands each
#define STHREADS 512

typedef __attribute__((ext_vector_type(2))) _Float16 half2_t;

static __device__ __forceinline__ half2_t bch(unsigned u) {
    return __builtin_bit_cast(half2_t, u);
}
static __device__ __forceinline__ half2_t habs2(half2_t x) {
    unsigned u = __builtin_bit_cast(unsigned, x) & 0x7fff7fffu;
    return __builtin_bit_cast(half2_t, u);
}
static __device__ __forceinline__ unsigned pkh(float x, float y) {
    half2_t h;
    h.x = (_Float16)x;
    h.y = (_Float16)y;
    return __builtin_bit_cast(unsigned, h);
}
static __device__ __forceinline__ float dot2acc(half2_t m, float s) {
#if __has_builtin(__builtin_amdgcn_fdot2)
    const half2_t ones = {(_Float16)1.f, (_Float16)1.f};
    return __builtin_amdgcn_fdot2(m, ones, s, false);
#else
    return s + (float)m.x + (float)m.y;
#endif
}

// ---- setup (R21 verbatim): dense16 = gathered f16 table; transposed q/o; base ----
__global__ void setup_kernel(const float* __restrict__ ent,
                             const float* __restrict__ relc,
                             const float* __restrict__ relo,
                             const float* __restrict__ onev,
                             const int*   __restrict__ pairs,
                             const int*   __restrict__ cidx,
                             uint4* __restrict__ dense16,
                             uint4* __restrict__ q16t,
                             uint4* __restrict__ o16t,
                             float* __restrict__ baseg) {
    const int blk = blockIdx.x;
    const int tid = threadIdx.x;
    if (blk < CVTBLK) {
        int i = blk * 256 + tid;                  // uint4 index: row*50 + col
        if (i >= CVTN) return;
        int row = i / 50;
        int col = i - row * 50;
        int n  = row < NCAND ? row : NCAND - 1;
        int ci = cidx[n];
        const float4* s4 = (const float4*)(ent + (size_t)ci * DIM) + col * 2;
        float4 a = s4[0], c = s4[1];
        uint4 d;
        d.x = pkh(a.x, a.y);
        d.y = pkh(a.z, a.w);
        d.z = pkh(c.x, c.y);
        d.w = pkh(c.z, c.w);
        dense16[i] = d;
    } else {
        const int b = blk - CVTBLK;
        const int h = pairs[2 * b + 0];
        const int r = pairs[2 * b + 1];
        float so = 0.f;
        if (tid < 50) {
            const float4* hp = (const float4*)(ent  + (size_t)h * DIM) + 2 * tid;
            const float4* cp = (const float4*)(relc + (size_t)r * DIM) + 2 * tid;
            const float4* op = (const float4*)(relo + (size_t)r * DIM) + 2 * tid;
            float4 h0 = hp[0], h1 = hp[1];
            float4 c0 = cp[0], c1 = cp[1];
            float4 v0 = op[0], v1 = op[1];
            uint4 qv, ov;
            qv.x = pkh(h0.x + c0.x, h0.y + c0.y);
            qv.y = pkh(h0.z + c0.z, h0.w + c0.w);
            qv.z = pkh(h1.x + c1.x, h1.y + c1.y);
            qv.w = pkh(h1.z + c1.z, h1.w + c1.w);
            ov.x = pkh(0.98f * v0.x, 0.98f * v0.y);
            ov.y = pkh(0.98f * v0.z, 0.98f * v0.w);
            ov.z = pkh(0.98f * v1.x, 0.98f * v1.y);
            ov.w = pkh(0.98f * v1.z, 0.98f * v1.w);
            q16t[tid * 32 + b] = qv;
            o16t[tid * 32 + b] = ov;
            so = v0.x + v0.y + v0.z + v0.w + v1.x + v1.y + v1.z + v1.w;
        }
        if (tid < 64) {
            so += __shfl_xor(so, 1);
            so += __shfl_xor(so, 2);
            so += __shfl_xor(so, 4);
            so += __shfl_xor(so, 8);
            so += __shfl_xor(so, 16);
            so += __shfl_xor(so, 32);
            if (tid == 0) baseg[b] = onev[0] + 0.98f * so;
        }
    }
}

// ---- main: R21's broadcast structure + R22's improvements ----
// 512 thr (8 waves) -> 2 blocks/CU at 53.7 KB LDS = 4 waves/SIMD (R21 had 1).
// Wave = 2 cand-slots x 32 batches, TWO pairs per j-pass: qj/oj ds_read once,
// applied to 4 candidates. Candidates from dense16: sequential f16, no gather,
// no pack (R22's regression source removed).
__global__ __launch_bounds__(STHREADS, 2)
void score_f16(const uint4* __restrict__ dense16,
               const uint4* __restrict__ q16t,
               const uint4* __restrict__ o16t,
               const float* __restrict__ baseg,
               float* __restrict__ out) {
    __shared__ uint4 qs[1600];           // [j][b], j=0..49, b=0..31
    __shared__ uint4 os[1600];
    const int tid = threadIdx.x;
    for (int i = tid; i < 1600; i += STHREADS) {
        qs[i] = q16t[i];
        os[i] = o16t[i];
    }
    __syncthreads();

    const int wid  = tid >> 6;           // 0..7
    const int lane = tid & 63;
    const int b    = lane & 31;          // batch
    const int c2   = lane >> 5;          // candidate within pair
    const float base = baseg[b];

    const int p0    = blockIdx.x * 16 + wid * 2;
    const int candA = 2 * p0 + c2;
    const int candB = candA + 2;
    const uint4* rA = dense16 + (size_t)candA * 50;
    const uint4* rB = dense16 + (size_t)candB * 50;

    const half2_t K002 = {(_Float16)0.02f, (_Float16)0.02f};

#define PAIRE(cu, qu, ou, SS)                                   \
    {                                                           \
        half2_t cc_ = bch(cu), qq_ = bch(qu), oo_ = bch(ou);    \
        half2_t dd_ = cc_ - qq_;                                \
        half2_t aa_ = habs2(dd_);                               \
        half2_t ee_ = aa_ * K002 + oo_;                         \
        half2_t mm_ = __builtin_elementwise_max(aa_, ee_);      \
        SS = dot2acc(mm_, SS);                                  \
    }
#define PROC(C, Q, O, SA, SB)                                   \
    PAIRE(C.x, Q.x, O.x, SA) PAIRE(C.y, Q.y, O.y, SB)           \
    PAIRE(C.z, Q.z, O.z, SA) PAIRE(C.w, Q.w, O.w, SB)

    float sA0 = 0.f, sA1 = 0.f, sB0 = 0.f, sB1 = 0.f;
#pragma unroll 5
    for (int j = 0; j < 50; ++j) {
        uint4 ca = rA[j];
        uint4 ce = rB[j];
        const uint4 qj = qs[(j << 5) | b];
        const uint4 oj = os[(j << 5) | b];
        PROC(ca, qj, oj, sA0, sA1)
        PROC(ce, qj, oj, sB0, sB1)
    }
#undef PROC
#undef PAIRE

    if (candA < NCAND)
        out[(size_t)b * NCAND + candA] = base - (sA0 + sA1);
    if (candB < NCAND)
        out[(size_t)b * NCAND + candB] = base - (sB0 + sB1);
}

// ---- fallback (no ws): R9 f32 kernel verbatim ----
__global__ __launch_bounds__(256, 2)
void score_f32(const float* __restrict__ ent,
               const float* __restrict__ relc,
               const float* __restrict__ relo,
               const float* __restrict__ onev,
               const int*   __restrict__ pairs,
               const int*   __restrict__ cidx,
               float* __restrict__ out) {
    const int fid  = blockIdx.x;
    const int xcd  = fid & 7;
    const int rest = fid >> 3;
    const int bq   = rest & 7;
    const int tc   = rest >> 3;
    const int t    = xcd + 8 * tc;

    const int tid  = threadIdx.x;
    const int lane = tid & 63;
    const int u    = lane & 15;
    const int g    = lane >> 4;
    const int b    = __builtin_amdgcn_readfirstlane(bq * 4 + (tid >> 6));

    const int hd = pairs[b * 2 + 0];
    const int rl = pairs[b * 2 + 1];
    const float4* hb = (const float4*)(ent  + (size_t)hd * DIM) + u;
    const float4* cb = (const float4*)(relc + (size_t)rl * DIM) + u;
    const float4* ob = (const float4*)(relo + (size_t)rl * DIM) + u;

    float4 q[7], o[7];
    float oa = 0.f;
#pragma unroll
    for (int k = 0; k < 6; ++k) {
        float4 h = hb[16 * k], c = cb[16 * k];
        q[k] = make_float4(h.x + c.x, h.y + c.y, h.z + c.z, h.w + c.w);
        o[k] = ob[16 * k];
        oa += o[k].x + o[k].y + o[k].z + o[k].w;
    }
    if (u < 4) {
        float4 h = hb[96], c = cb[96];
        q[6] = make_float4(h.x + c.x, h.y + c.y, h.z + c.z, h.w + c.w);
        o[6] = ob[96];
        oa += o[6].x + o[6].y + o[6].z + o[6].w;
    }
    oa += __shfl_xor(oa, 1);
    oa += __shfl_xor(oa, 2);
    oa += __shfl_xor(oa, 4);
    oa += __shfl_xor(oa, 8);
    const float base = onev[0] + 0.98f * oa;

    const float4* entu = (const float4*)ent + u;

#define E(vc, vq, vo, AM, AD)                     \
        {                                         \
            float d_ = (vc) - (vq);               \
            AM += fmaxf(fabsf(d_), (vo));         \
            AD += fabsf(d_);                      \
        }
#define F4(k, AM, AD)                             \
        E(cbuf[k].x, q[k].x, o[k].x, AM, AD)      \
        E(cbuf[k].y, q[k].y, o[k].y, AM, AD)      \
        E(cbuf[k].z, q[k].z, o[k].z, AM, AD)      \
        E(cbuf[k].w, q[k].w, o[k].w, AM, AD)

    for (int rr = t; rr < 3627; rr += 256) {
        const int cand = 4 * rr + g;
        const int ci   = cidx[cand < NCAND ? cand : NCAND - 1];
        const float4* p = entu + (size_t)ci * 100;

        float4 cbuf[7];
#pragma unroll
        for (int k = 0; k < 6; ++k) cbuf[k] = p[16 * k];
        if (u < 4) cbuf[6] = p[96];

        float am0 = 0.f, ad0 = 0.f, am1 = 0.f, ad1 = 0.f;
        F4(0, am0, ad0) F4(1, am1, ad1)
        F4(2, am0, ad0) F4(3, am1, ad1)
        F4(4, am0, ad0) F4(5, am1, ad1)
        if (u < 4) { F4(6, am0, ad0) }

        float s_ = fmaf(-0.98f, am0 + am1, -0.02f * (ad0 + ad1));
        s_ += __shfl_xor(s_, 1);
        s_ += __shfl_xor(s_, 2);
        s_ += __shfl_xor(s_, 4);
        s_ += __shfl_xor(s_, 8);

        if (u == 0 && cand < NCAND)
            out[(size_t)b * NCAND + cand] = base + s_;
    }
#undef F4
#undef E
}

extern "C" void kernel_launch(void* const* d_in, const int* in_sizes, int n_in,
                              void* d_out, int out_size, void* d_ws, size_t ws_size,
                              hipStream_t stream) {
    const float* ent   = (const float*)d_in[0];
    const float* relc  = (const float*)d_in[1];
    const float* relo  = (const float*)d_in[2];
    const float* onev  = (const float*)d_in[3];
    const int*   pairs = (const int*)d_in[4];
    const int*   cidx  = (const int*)d_in[5];
    float*       out   = (float*)d_out;

    const size_t denB = (size_t)DROWS * DIM * 2;     // 11,648,000 B
    const size_t qB   = (size_t)1600 * 16;           // 25,600 B per table
    const size_t need = denB + 2 * qB + B * sizeof(float);

    if (ws_size >= need) {
        unsigned char* w = (unsigned char*)d_ws;
        uint4* dense16 = (uint4*)w;
        uint4* q16t    = (uint4*)(w + denB);
        uint4* o16t    = (uint4*)(w + denB + qB);
        float* baseg   = (float*)(w + denB + 2 * qB);

        setup_kernel<<<CVTBLK + B, 256, 0, stream>>>(
            ent, relc, relo, onev, pairs, cidx, dense16, q16t, o16t, baseg);
        score_f16<<<NBLK, STHREADS, 0, stream>>>(
            dense16, q16t, o16t, baseg, out);
    } else {
        score_f32<<<8 * 8 * 32, 256, 0, stream>>>(
            ent, relc, relo, onev, pairs, cidx, out);
    }
}